// Round 8
// baseline (160.068 us; speedup 1.0000x reference)
//
#include <hip/hip_runtime.h>

// EmbedDNF: B=128, IN_F=256, HID=512, OUT=128, E=8 (fp32, e innermost)
//
// impl = 1 - w*(1-xnor) = A + x*Bv ; A = 1 - w*s ; Bv = 2*w*s - w
// H[b,h,e]   = prod_i (A[i,h,e] + x[b,i,e]*Bv[i,h,e])
// out[b,o,e] = 1 - prod_h (1 - dw[h,o,e]*H[b,h,e])
//
// R7 post-mortem: kernels ~40-45 us total, hidden under the ~43 us fills.
// Suspect: stage1's 8 ds_read_b128/step (LDS-pipe issue cost + lgkm/vm
// interleave). Fix: x is wave-uniform per (b,i) -> move it to the SCALAR
// path (s_load via uniform addresses; thread covers all 8 e, lane = h).
// Inner loop: 4 contiguous VMEM (w,s) + 8 scalar loads + VALU. No LDS.
//
// ws: P1 [8][512][128][8] fp32 @ 0        (16 MB)  stage1 i-split partials
//     P2 [8][128][128][8] fp32 @ 4194304  (4 MB)   stage2 h-split partials

#define LD4(p) (*(const float4*)(p))

static __device__ __forceinline__ float4 f4mul(float4 a, float4 b) {
    return make_float4(a.x*b.x, a.y*b.y, a.z*b.z, a.w*b.w);
}
static __device__ __forceinline__ float4 f4fma(float4 a, float4 b, float4 c) {
    return make_float4(fmaf(a.x,b.x,c.x), fmaf(a.y,b.y,c.y),
                       fmaf(a.z,b.z,c.z), fmaf(a.w,b.w,c.w));
}
static __device__ __forceinline__ float2 f2mul(float2 a, float2 b) {
    return make_float2(a.x*b.x, a.y*b.y);
}
static __device__ __forceinline__ float4 f4nfma1(float4 d, float4 h) {  // 1-d*h
    return make_float4(fmaf(-d.x,h.x,1.0f), fmaf(-d.y,h.y,1.0f),
                       fmaf(-d.z,h.z,1.0f), fmaf(-d.w,h.w,1.0f));
}

// ---------------------------------------------------------------------------
// Stage 1. Grid 1024 = hg8 (64 h, low bits: ~2 MB cw/cs slice per XCD) x
// bg16 (8 b) x ks8 (32 i). Block 256 = 4 waves = 4 i-subchunks of 8.
// Lane = h (full 64 h per wave); thread tile 8b x 1h x 8e (acc = 64 VGPR).
// Per step: w,s = 4 contiguous float4 wave-loads (2 KB each operand);
// x = 8x wave-uniform float4-pair loads -> scalar cache (no LDS, no VMEM
// broadcast). kc-partials combined via 34 KB pitch-34 LDS scratch (2 phases).
// ---------------------------------------------------------------------------
__global__ __launch_bounds__(256, 4) void k_stage1(
    const float* __restrict__ in,   // [128][256][8]
    const float* __restrict__ cw,   // [256][512][8]
    const float* __restrict__ cs,   // [256][512][8]
    float* __restrict__ P1)         // ws: [8][512][128][8]
{
    __shared__ float lds[8704];              // 34 KB: [kc4][lane64 pitch 34]
    const int t    = threadIdx.x;
    const int lane = t & 63;
    const int kc   = __builtin_amdgcn_readfirstlane(t >> 6);  // wave id 0..3
    const int hg   = blockIdx.x & 7;
    const int bg   = (blockIdx.x >> 3) & 15;
    const int ks   = blockIdx.x >> 7;        // 0..7
    const int b0   = bg * 8;
    const int h    = hg * 64 + lane;
    const int i0   = ks * 32 + kc * 8;       // this wave's 8 i

    const float* pw = cw + i0 * 4096 + h * 8;
    const float* ps = cs + i0 * 4096 + h * 8;
    const float* px = in + b0 * 2048 + i0 * 8;   // wave-uniform base

    float4 acc[8][2];                        // [b][e-quad]
    #pragma unroll
    for (int b = 0; b < 8; ++b) {
        acc[b][0] = make_float4(1.f, 1.f, 1.f, 1.f);
        acc[b][1] = make_float4(1.f, 1.f, 1.f, 1.f);
    }

    #pragma unroll
    for (int ii = 0; ii < 8; ++ii) {
        const float4 w0 = LD4(pw);           // e 0..3 (lane-contiguous 2 KB)
        const float4 w1 = LD4(pw + 4);       // e 4..7
        const float4 s0 = LD4(ps);
        const float4 s1 = LD4(ps + 4);
        pw += 4096; ps += 4096;
        const float4 p0 = f4mul(w0, s0);
        const float4 p1 = f4mul(w1, s1);
        const float4 A0 = make_float4(1.f - p0.x, 1.f - p0.y, 1.f - p0.z, 1.f - p0.w);
        const float4 A1 = make_float4(1.f - p1.x, 1.f - p1.y, 1.f - p1.z, 1.f - p1.w);
        const float4 B0 = make_float4(fmaf(2.f, p0.x, -w0.x), fmaf(2.f, p0.y, -w0.y),
                                      fmaf(2.f, p0.z, -w0.z), fmaf(2.f, p0.w, -w0.w));
        const float4 B1 = make_float4(fmaf(2.f, p1.x, -w1.x), fmaf(2.f, p1.y, -w1.y),
                                      fmaf(2.f, p1.z, -w1.z), fmaf(2.f, p1.w, -w1.w));
        #pragma unroll
        for (int b = 0; b < 8; ++b) {
            const float* xb = px + b * 2048 + ii * 8;   // uniform -> s_load
            const float4 x0 = LD4(xb);
            const float4 x1 = LD4(xb + 4);
            acc[b][0] = f4mul(acc[b][0], f4fma(x0, B0, A0));
            acc[b][1] = f4mul(acc[b][1], f4fma(x1, B1, A1));
        }
    }

    // combine 4 kc-partials; 2 phases of 4 b each (34 KB scratch, pitch 34:
    // write 4-way bank aliasing, read 2-way -> negligible, once per block)
    #pragma unroll
    for (int phase = 0; phase < 2; ++phase) {
        if (phase) __syncthreads();          // protect phase-0 reads
        #pragma unroll
        for (int j = 0; j < 4; ++j) {
            const int bb = phase * 4 + j;
            float* q = &lds[kc * 2176 + lane * 34 + j * 8];
            *(float2*)(q)     = make_float2(acc[bb][0].x, acc[bb][0].y);
            *(float2*)(q + 2) = make_float2(acc[bb][0].z, acc[bb][0].w);
            *(float2*)(q + 4) = make_float2(acc[bb][1].x, acc[bb][1].y);
            *(float2*)(q + 6) = make_float2(acc[bb][1].z, acc[bb][1].w);
        }
        __syncthreads();
        {   // thread -> (h2 = t>>2, j2 = t&3): one (h,b) row of 8 e
            const int h2 = t >> 2, j2 = t & 3;
            const int base = h2 * 34 + j2 * 8;
            float2 m0 = *(const float2*)&lds[base];
            float2 m1 = *(const float2*)&lds[base + 2];
            float2 m2 = *(const float2*)&lds[base + 4];
            float2 m3 = *(const float2*)&lds[base + 6];
            #pragma unroll
            for (int c = 1; c < 4; ++c) {
                const float* q = &lds[c * 2176 + base];
                m0 = f2mul(m0, *(const float2*)(q));
                m1 = f2mul(m1, *(const float2*)(q + 2));
                m2 = f2mul(m2, *(const float2*)(q + 4));
                m3 = f2mul(m3, *(const float2*)(q + 6));
            }
            float* o = P1 + ks * 524288 + (hg * 64 + h2) * 1024
                          + (b0 + phase * 4 + j2) * 8;
            *(float4*)(o)     = make_float4(m0.x, m0.y, m1.x, m1.y);
            *(float4*)(o + 4) = make_float4(m2.x, m2.y, m3.x, m3.y);
        }
    }
}

// ---------------------------------------------------------------------------
// Stage 2 (R7 structure, 8-copy P1 combine). Grid 512 = og4 (32 o, low bits)
// x bg16 (8 b) x ks8 (64 h). Block 256 = 4 waves = 4 h-subchunks of 16.
// Lane = eh2 x ol32. Prologue: H-tile [64 h][8 b][8 e] = prod of 8 P1
// partials -> LDS. Step: 1 contiguous dw wave-load + 8 immediate-offset
// ds_reads + 64 VALU. kc-partials combined in LDS; ks-partials -> P2.
// ---------------------------------------------------------------------------
__global__ __launch_bounds__(256, 4) void k_stage2(
    const float* __restrict__ dw,   // [512][128][8]
    const float* __restrict__ P1,   // ws: [8][512][128][8]
    float* __restrict__ P2)         // ws: [8][128][128][8]
{
    __shared__ float lds[8192];              // 32 KB: H-tile then combine
    const int t    = threadIdx.x;
    const int lane = t & 63;
    const int kc   = t >> 6;                 // 0..3
    const int eh   = lane & 1;
    const int ol   = lane >> 1;              // 0..31
    const int og   = blockIdx.x & 3;
    const int bg   = (blockIdx.x >> 2) & 15;
    const int ks   = blockIdx.x >> 6;        // 0..7
    const int b0   = bg * 8;
    const int o    = og * 32 + ol;
    const int e0   = eh * 4;
    const int h0   = ks * 64;

    // H-tile: product of the 8 i-split partials, layout [hl][b][e]
    {
        float4* ht4 = (float4*)lds;
        #pragma unroll
        for (int k = 0; k < 4; ++k) {
            const int f4  = t + k * 256;     // 0..1023
            const int hl  = f4 >> 4;
            const int rem = f4 & 15;         // b*2 + eq
            const float* q = P1 + (h0 + hl) * 1024 + b0 * 8 + rem * 4;
            float4 m = LD4(q);
            #pragma unroll
            for (int c = 1; c < 8; ++c) m = f4mul(m, LD4(q + c * 524288));
            ht4[f4] = m;
        }
    }
    __syncthreads();

    const float* pd = dw + (h0 + kc * 16) * 1024 + o * 8 + e0;
    const float* hbase = lds + kc * 1024 + e0;  // + ii*64 + b*8 (immediates)

    float4 acc[8];
    #pragma unroll
    for (int b = 0; b < 8; ++b) acc[b] = make_float4(1.f, 1.f, 1.f, 1.f);

    #pragma unroll
    for (int ii = 0; ii < 16; ++ii) {
        const float4 dv = LD4(pd);
        pd += 1024;
        #pragma unroll
        for (int b = 0; b < 8; ++b) {
            const float4 hv = LD4(hbase + ii * 64 + b * 8);
            acc[b] = f4mul(acc[b], f4nfma1(dv, hv));
        }
    }

    __syncthreads();                         // H-tile dead; reuse lds
    #pragma unroll
    for (int b = 0; b < 8; ++b)
        *(float4*)&lds[kc * 2048 + b * 256 + ol * 8 + e0] = acc[b];
    __syncthreads();

    {   // combine 4 kc; one (b,o) row of 8 e per thread
        const int bq  = t >> 5;
        const int ol2 = t & 31;
        const int base = bq * 256 + ol2 * 8;
        float4 m0 = LD4(&lds[base]);
        float4 m1 = LD4(&lds[base + 4]);
        #pragma unroll
        for (int c = 1; c < 4; ++c) {
            m0 = f4mul(m0, LD4(&lds[c * 2048 + base]));
            m1 = f4mul(m1, LD4(&lds[c * 2048 + base + 4]));
        }
        float* q = P2 + ks * 131072 + (b0 + bq) * 1024 + (og * 32 + ol2) * 8;
        *(float4*)q = m0;
        *(float4*)(q + 4) = m1;
    }
}

// ---------------------------------------------------------------------------
// Final: out = 1 - prod over the 8 h-split partials. 4 MB read, 0.5 MB write.
// ---------------------------------------------------------------------------
__global__ __launch_bounds__(256, 4) void k_comb2(
    const float* __restrict__ P2,   // ws: [8][128][128][8]
    float* __restrict__ out)        // [128][128][8]
{
    const int idx4 = blockIdx.x * 256 + threadIdx.x;   // 0..32767
    float4 m = LD4(P2 + idx4 * 4);
    #pragma unroll
    for (int c = 1; c < 8; ++c)
        m = f4mul(m, LD4(P2 + c * 131072 + idx4 * 4));
    const float4 r = make_float4(1.f - m.x, 1.f - m.y, 1.f - m.z, 1.f - m.w);
    *(float4*)(out + idx4 * 4) = r;
}

extern "C" void kernel_launch(void* const* d_in, const int* in_sizes, int n_in,
                              void* d_out, int out_size, void* d_ws, size_t ws_size,
                              hipStream_t stream)
{
    const float* in = (const float*)d_in[0];   // [128][256][8]
    const float* cw = (const float*)d_in[1];   // [256][512][8]
    const float* cs = (const float*)d_in[2];   // [256][512][8]
    const float* dw = (const float*)d_in[3];   // [512][128][8]
    float* outp = (float*)d_out;               // [128][128][8]
    float* P1   = (float*)d_ws;                // 16 MB
    float* P2   = (float*)d_ws + 4194304;      // 4 MB

    k_stage1<<<1024, 256, 0, stream>>>(in, cw, cs, P1);
    k_stage2<<<512, 256, 0, stream>>>(dw, P1, P2);
    k_comb2<<<128, 256, 0, stream>>>(P2, outp);
}

// Round 9
// 157.499 us; speedup vs baseline: 1.0163x; 1.0163x over previous
//
#include <hip/hip_runtime.h>

// EmbedDNF: B=128, IN_F=256, HID=512, OUT=128, E=8 (fp32, e innermost)
//
// impl = 1 - w*(1-xnor) = A + x*Bv ; A = 1 - w*s ; Bv = 2*w*s - w
// H[b,h,e]   = prod_i (A[i,h,e] + x[b,i,e]*Bv[i,h,e])
// out[b,o,e] = 1 - prod_h (1 - dw[h,o,e]*H[b,h,e])
//
// R8 post-mortem: scalar-path x loads never materialized; 64-VGPR acc spilled
// (3rd spill regression). Law: acc must stay <=32 VGPR; x broadcasts belong
// in LDS; <=2 VMEM streams per loop. This file = R7 (proven 97.3 us, kernels
// all <43 us) + comb2 merged into stage2 via split-K atomic-counter fixup
// (node-count test: is the residual ~44 us kernels or graph gaps?).
//
// ws: P1  [4][512][128][8] fp32 @ 0        (8 MB)   stage1 i-split partials
//     P2  [8][128][128][8] fp32 @ 2097152  (4 MB)   stage2 h-split partials
//     cnt [64] int         @ 3145728               family counters (stage1 zeroes)

#define LD4(p) (*(const float4*)(p))

static __device__ __forceinline__ float4 f4mul(float4 a, float4 b) {
    return make_float4(a.x*b.x, a.y*b.y, a.z*b.z, a.w*b.w);
}
static __device__ __forceinline__ float4 f4fma(float4 a, float4 b, float4 c) {
    return make_float4(fmaf(a.x,b.x,c.x), fmaf(a.y,b.y,c.y),
                       fmaf(a.z,b.z,c.z), fmaf(a.w,b.w,c.w));
}
static __device__ __forceinline__ float4 f4nfma1(float4 d, float4 h) {  // 1-d*h
    return make_float4(fmaf(-d.x,h.x,1.0f), fmaf(-d.y,h.y,1.0f),
                       fmaf(-d.z,h.z,1.0f), fmaf(-d.w,h.w,1.0f));
}

// ---------------------------------------------------------------------------
// Stage 1 (R7 verbatim + counter zeroing). Grid 1024 = hg16 (32 h, low bits:
// XCD L2 slicing) x bg16 (8 b) x ks4 (64 i). Block 256 = 4 waves = 4
// i-subchunks of 16. Lane = eh2 x hl32; thread tile 8b x 1h x 4e (acc=32 VGPR).
// Prologue: x-tile [8 b][64 i][8 e] (16 KB) -> LDS, coalesced.
// Step: 2 streaming VMEM (w,s contiguous 1 KB wave-loads) + 8 immediate-offset
// ds_read_b128 broadcasts + ~76 VALU. kc-partials combined in reused LDS.
// ---------------------------------------------------------------------------
__global__ __launch_bounds__(256, 4) void k_stage1(
    const float* __restrict__ in,   // [128][256][8]
    const float* __restrict__ cw,   // [256][512][8]
    const float* __restrict__ cs,   // [256][512][8]
    float* __restrict__ P1,         // ws: [4][512][128][8]
    int* __restrict__ cnt)          // ws: [64]
{
    __shared__ float lds[8192];              // 32 KB: x-tile [0,4096) then combine
    const int t    = threadIdx.x;
    const int lane = t & 63;
    const int kc   = t >> 6;                 // 0..3
    const int eh   = lane & 1;
    const int hl   = lane >> 1;              // 0..31
    const int hg   = blockIdx.x & 15;
    const int bg   = (blockIdx.x >> 4) & 15;
    const int ks   = blockIdx.x >> 8;        // 0..3
    const int b0   = bg * 8;
    const int h    = hg * 32 + hl;
    const int e0   = eh * 4;

    // reset the stage2 fixup counters (whole kernel completes before stage2)
    if (blockIdx.x < 64 && t == 0) cnt[blockIdx.x] = 0;

    // stage x[b0:+8][ks*64:+64][0:8] -> lds (layout [b][il][e]), coalesced
    {
        float4* xs4 = (float4*)lds;
        #pragma unroll
        for (int k = 0; k < 4; ++k) {
            const int f4  = t + k * 256;     // 0..1023
            const int b   = f4 >> 7;
            const int col = f4 & 127;        // float4 within 512 B row
            xs4[b * 128 + col] = LD4(in + (b0 + b) * 2048 + ks * 512 + col * 4);
        }
    }
    __syncthreads();

    const int i0 = (ks * 4 + kc) * 16;
    const float* pw = cw + i0 * 4096 + h * 8 + e0;
    const float* ps = cs + i0 * 4096 + h * 8 + e0;
    const float* xbase = lds + kc * 128 + e0;   // + b*512 + ii*8 (immediates)

    float4 acc[8];
    #pragma unroll
    for (int b = 0; b < 8; ++b) acc[b] = make_float4(1.f, 1.f, 1.f, 1.f);

    #pragma unroll
    for (int ii = 0; ii < 16; ++ii) {
        const float4 wv = LD4(pw);
        const float4 sv = LD4(ps);
        pw += 4096; ps += 4096;
        const float4 p  = f4mul(wv, sv);
        const float4 A  = make_float4(1.f - p.x, 1.f - p.y, 1.f - p.z, 1.f - p.w);
        const float4 Bv = make_float4(fmaf(2.f, p.x, -wv.x), fmaf(2.f, p.y, -wv.y),
                                      fmaf(2.f, p.z, -wv.z), fmaf(2.f, p.w, -wv.w));
        #pragma unroll
        for (int b = 0; b < 8; ++b) {
            const float4 xv = LD4(xbase + b * 512 + ii * 8);
            acc[b] = f4mul(acc[b], f4fma(xv, Bv, A));
        }
    }

    __syncthreads();                         // x-tile dead; reuse lds
    #pragma unroll
    for (int b = 0; b < 8; ++b)
        *(float4*)&lds[kc * 2048 + b * 256 + hl * 8 + e0] = acc[b];
    __syncthreads();

    {   // combine 4 kc; one (b,h) row of 8 e per thread; 32 B global store
        const int bq  = t >> 5;
        const int hl2 = t & 31;
        const int base = bq * 256 + hl2 * 8;
        float4 m0 = LD4(&lds[base]);
        float4 m1 = LD4(&lds[base + 4]);
        #pragma unroll
        for (int c = 1; c < 4; ++c) {
            m0 = f4mul(m0, LD4(&lds[c * 2048 + base]));
            m1 = f4mul(m1, LD4(&lds[c * 2048 + base + 4]));
        }
        float* q = P1 + ks * 524288 + (hg * 32 + hl2) * 1024 + (b0 + bq) * 8;
        *(float4*)q = m0;
        *(float4*)(q + 4) = m1;
    }
}

// ---------------------------------------------------------------------------
// Stage 2 (R7 structure) + split-K fixup replacing k_comb2.
// Grid 512 = og4 (32 o, low bits) x bg16 (8 b) x ks8 (64 h). Block 256 =
// 4 waves = 4 h-subchunks of 16. Lane = eh2 x ol32; tile 8b x 1o x 4e.
// Prologue: H-tile [64 h][8 b][8 e] = product of 4 P1 partials -> LDS.
// Step: 1 contiguous dw wave-load + 8 immediate-offset ds_reads + 64 VALU.
// Tail: write P2 partial; last block of the 8-member (og,bg) family
// (device-scope counter + threadfence release/acquire) combines all 8 and
// writes out = 1 - prod.
// ---------------------------------------------------------------------------
__global__ __launch_bounds__(256, 4) void k_stage2(
    const float* __restrict__ dw,   // [512][128][8]
    const float* __restrict__ P1,   // ws: [4][512][128][8]
    float* __restrict__ P2,         // ws: [8][128][128][8]
    int* __restrict__ cnt,          // ws: [64]
    float* __restrict__ out)        // [128][128][8]
{
    __shared__ float lds[8192];              // 32 KB: H-tile then combine
    __shared__ int last_flag;
    const int t    = threadIdx.x;
    const int lane = t & 63;
    const int kc   = t >> 6;                 // 0..3
    const int eh   = lane & 1;
    const int ol   = lane >> 1;              // 0..31
    const int og   = blockIdx.x & 3;
    const int bg   = (blockIdx.x >> 2) & 15;
    const int ks   = blockIdx.x >> 6;        // 0..7
    const int fam  = blockIdx.x & 63;        // (og,bg) family
    const int b0   = bg * 8;
    const int o    = og * 32 + ol;
    const int e0   = eh * 4;
    const int h0   = ks * 64;

    // H-tile: product of the 4 i-split partials, layout [hl][b][e]
    {
        float4* ht4 = (float4*)lds;
        #pragma unroll
        for (int k = 0; k < 4; ++k) {
            const int f4  = t + k * 256;     // 0..1023
            const int hl  = f4 >> 4;
            const int rem = f4 & 15;         // b*2 + eq
            const float* q = P1 + (h0 + hl) * 1024 + b0 * 8 + rem * 4;
            float4 m = LD4(q);
            m = f4mul(m, LD4(q + 524288));
            m = f4mul(m, LD4(q + 1048576));
            m = f4mul(m, LD4(q + 1572864));
            ht4[f4] = m;
        }
    }
    __syncthreads();

    const float* pd = dw + (h0 + kc * 16) * 1024 + o * 8 + e0;
    const float* hbase = lds + kc * 1024 + e0;  // + ii*64 + b*8 (immediates)

    float4 acc[8];
    #pragma unroll
    for (int b = 0; b < 8; ++b) acc[b] = make_float4(1.f, 1.f, 1.f, 1.f);

    #pragma unroll
    for (int ii = 0; ii < 16; ++ii) {
        const float4 dv = LD4(pd);
        pd += 1024;
        #pragma unroll
        for (int b = 0; b < 8; ++b) {
            const float4 hv = LD4(hbase + ii * 64 + b * 8);
            acc[b] = f4mul(acc[b], f4nfma1(dv, hv));
        }
    }

    __syncthreads();                         // H-tile dead; reuse lds
    #pragma unroll
    for (int b = 0; b < 8; ++b)
        *(float4*)&lds[kc * 2048 + b * 256 + ol * 8 + e0] = acc[b];
    __syncthreads();

    {   // combine 4 kc; one (b,o) row of 8 e per thread -> P2 partial
        const int bq  = t >> 5;
        const int ol2 = t & 31;
        const int base = bq * 256 + ol2 * 8;
        float4 m0 = LD4(&lds[base]);
        float4 m1 = LD4(&lds[base + 4]);
        #pragma unroll
        for (int c = 1; c < 4; ++c) {
            m0 = f4mul(m0, LD4(&lds[c * 2048 + base]));
            m1 = f4mul(m1, LD4(&lds[c * 2048 + base + 4]));
        }
        float* q = P2 + ks * 131072 + (b0 + bq) * 1024 + (og * 32 + ol2) * 8;
        *(float4*)q = m0;
        *(float4*)(q + 4) = m1;
    }

    // ---- split-K fixup: last family member combines the 8 partials ----
    __threadfence();                         // release our P2 writes
    if (t == 0) {
        const int old = atomicAdd(cnt + fam, 1);
        last_flag = (old == 7);
    }
    __syncthreads();
    if (last_flag) {
        __threadfence();                     // acquire others' P2 writes
        const int bq  = t >> 5;
        const int ol2 = t & 31;
        const float* q = P2 + (b0 + bq) * 1024 + (og * 32 + ol2) * 8;
        float4 m0 = LD4(q);
        float4 m1 = LD4(q + 4);
        #pragma unroll
        for (int c = 1; c < 8; ++c) {
            m0 = f4mul(m0, LD4(q + c * 131072));
            m1 = f4mul(m1, LD4(q + c * 131072 + 4));
        }
        float* po = out + (b0 + bq) * 1024 + (og * 32 + ol2) * 8;
        *(float4*)(po)     = make_float4(1.f - m0.x, 1.f - m0.y, 1.f - m0.z, 1.f - m0.w);
        *(float4*)(po + 4) = make_float4(1.f - m1.x, 1.f - m1.y, 1.f - m1.z, 1.f - m1.w);
    }
}

extern "C" void kernel_launch(void* const* d_in, const int* in_sizes, int n_in,
                              void* d_out, int out_size, void* d_ws, size_t ws_size,
                              hipStream_t stream)
{
    const float* in = (const float*)d_in[0];   // [128][256][8]
    const float* cw = (const float*)d_in[1];   // [256][512][8]
    const float* cs = (const float*)d_in[2];   // [256][512][8]
    const float* dw = (const float*)d_in[3];   // [512][128][8]
    float* outp = (float*)d_out;               // [128][128][8]
    float* P1   = (float*)d_ws;                // 8 MB
    float* P2   = (float*)d_ws + 2097152;      // 4 MB
    int*   cnt  = (int*)((float*)d_ws + 3145728);

    k_stage1<<<1024, 256, 0, stream>>>(in, cw, cs, P1, cnt);
    k_stage2<<<512, 256, 0, stream>>>(dw, P1, P2, cnt, outp);
}

// Round 10
// 144.718 us; speedup vs baseline: 1.1061x; 1.0883x over previous
//
#include <hip/hip_runtime.h>

// EmbedDNF: B=128, IN_F=256, HID=512, OUT=128, E=8 (fp32, e innermost)
//
// impl = 1 - w*(1-xnor) = A + x*Bv ; A = 1 - w*s ; Bv = 2*w*s - w
// H[b,h,e]   = prod_i (A[i,h,e] + x[b,i,e]*Bv[i,h,e])
// out[b,o,e] = 1 - prod_h (1 - dw[h,o,e]*H[b,h,e])
//
// Laws learned R4-R9: (1) acc <= 32 VGPR or it spills (R5/R6/R8);
// (2) broadcast operands (x, H) live in LDS with immediate-offset reads,
//     <= 2 VMEM streams per loop (R7 = only fast config);
// (3) no device-scope fences/atomics in the hot path (R9: threadfence = 80us);
// (4) LDS issue cost is the next wall: 8 ds_read_b128/step ~ 96 cyc/wave.
// This round: retile 8b x 2h(2o) x 2e -> x/H reads become ds_read_b64
// (halves LDS cycles), h/o pair = (k, k+16) keeps VMEM 512 B-coalesced.
//
// ws: P1 [4][512][128][8] fp32 @ 0        (8 MB)  stage1 i-split partials
//     P2 [8][128][128][8] fp32 @ 2097152  (4 MB)  stage2 h-split partials

#define LD4(p) (*(const float4*)(p))
#define LD2(p) (*(const float2*)(p))

static __device__ __forceinline__ float4 f4mul(float4 a, float4 b) {
    return make_float4(a.x*b.x, a.y*b.y, a.z*b.z, a.w*b.w);
}
static __device__ __forceinline__ float2 f2mul(float2 a, float2 b) {
    return make_float2(a.x*b.x, a.y*b.y);
}
static __device__ __forceinline__ float2 f2fma(float2 a, float2 b, float2 c) {
    return make_float2(fmaf(a.x,b.x,c.x), fmaf(a.y,b.y,c.y));
}
static __device__ __forceinline__ float2 f2nfma1(float2 d, float2 h) {  // 1-d*h
    return make_float2(fmaf(-d.x,h.x,1.0f), fmaf(-d.y,h.y,1.0f));
}

// ---------------------------------------------------------------------------
// Stage 1. Grid 1024 = hg16 (32 h, low bits: XCD L2 slicing) x bg16 (8 b) x
// ks4 (64 i). Block 256 = 4 waves = 4 i-subchunks of 16.
// Lane = hs16 x es4; thread tile 8b x 2h x 2e, h-pair (hs, hs+16), e0=es*2.
// acc[8][2] float2 = 32 VGPR. Prologue: x-tile [8 b][64 i][8 e] -> LDS.
// Step: 4 coalesced VMEM b64 (w,s at lane-offset 2*lane: 512 B segments) +
// 8 immediate-offset ds_read_b64 (x) + ~40 pk-VALU.
// ---------------------------------------------------------------------------
__global__ __launch_bounds__(256, 4) void k_stage1(
    const float* __restrict__ in,   // [128][256][8]
    const float* __restrict__ cw,   // [256][512][8]
    const float* __restrict__ cs,   // [256][512][8]
    float* __restrict__ P1)         // ws: [4][512][128][8]
{
    __shared__ float lds[8192];              // 32 KB: x-tile [0,4096) then combine
    const int t    = threadIdx.x;
    const int lane = t & 63;
    const int kc   = t >> 6;                 // 0..3
    const int es   = lane & 3;
    const int hs   = lane >> 2;              // 0..15
    const int hg   = blockIdx.x & 15;
    const int bg   = (blockIdx.x >> 4) & 15;
    const int ks   = blockIdx.x >> 8;        // 0..3
    const int b0   = bg * 8;

    // stage x[b0:+8][ks*64:+64][0:8] -> lds (layout [b][il][e]), coalesced
    {
        float4* xs4 = (float4*)lds;
        #pragma unroll
        for (int k = 0; k < 4; ++k) {
            const int f4  = t + k * 256;     // 0..1023
            const int b   = f4 >> 7;
            const int col = f4 & 127;
            xs4[b * 128 + col] = LD4(in + (b0 + b) * 2048 + ks * 512 + col * 4);
        }
    }
    __syncthreads();

    const int i0 = ks * 64 + kc * 16;
    // lane-linear offset 2*lane -> contiguous 512 B per load
    const float* pw = cw + i0 * 4096 + hg * 256 + hs * 8 + es * 2;
    const float* ps = cs + i0 * 4096 + hg * 256 + hs * 8 + es * 2;
    const float* xbase = lds + kc * 128 + es * 2;   // + b*512 + ii*8 (immediates)

    float2 acc[8][2];                        // [b][hh], 32 VGPR
    #pragma unroll
    for (int b = 0; b < 8; ++b) {
        acc[b][0] = make_float2(1.f, 1.f);
        acc[b][1] = make_float2(1.f, 1.f);
    }

    #pragma unroll
    for (int ii = 0; ii < 16; ++ii) {
        const float2 w0 = LD2(pw);           // h = hg*32 + hs
        const float2 w1 = LD2(pw + 128);     // h = hg*32 + hs + 16
        const float2 s0 = LD2(ps);
        const float2 s1 = LD2(ps + 128);
        pw += 4096; ps += 4096;
        const float2 p0 = f2mul(w0, s0);
        const float2 p1 = f2mul(w1, s1);
        const float2 A0 = make_float2(1.f - p0.x, 1.f - p0.y);
        const float2 A1 = make_float2(1.f - p1.x, 1.f - p1.y);
        const float2 B0 = make_float2(fmaf(2.f, p0.x, -w0.x), fmaf(2.f, p0.y, -w0.y));
        const float2 B1 = make_float2(fmaf(2.f, p1.x, -w1.x), fmaf(2.f, p1.y, -w1.y));
        #pragma unroll
        for (int b = 0; b < 8; ++b) {
            const float2 xv = LD2(xbase + b * 512 + ii * 8);   // ds_read_b64
            acc[b][0] = f2mul(acc[b][0], f2fma(xv, B0, A0));
            acc[b][1] = f2mul(acc[b][1], f2fma(xv, B1, A1));
        }
    }

    __syncthreads();                         // x-tile dead; reuse lds
    // part[kc][b][h_loc][e], h_loc = hs + hh*16
    #pragma unroll
    for (int b = 0; b < 8; ++b) {
        #pragma unroll
        for (int hh = 0; hh < 2; ++hh)
            *(float2*)&lds[kc * 2048 + b * 256 + (hs + hh * 16) * 8 + es * 2]
                = acc[b][hh];
    }
    __syncthreads();

    {   // combine 4 kc; thread -> (h_loc = t>>3, f4i = t&7); 128 B-segment stores
        const int h_loc = t >> 3;
        const int f4i   = t & 7;             // b_lo*2 + eh
        const int roff  = (f4i >> 1) * 256 + h_loc * 8 + (f4i & 1) * 4;
        float4 m0 = LD4(&lds[roff]);         // b_loc = f4i>>1
        float4 m1 = LD4(&lds[roff + 1024]);  // b_loc + 4
        #pragma unroll
        for (int c = 1; c < 4; ++c) {
            m0 = f4mul(m0, LD4(&lds[c * 2048 + roff]));
            m1 = f4mul(m1, LD4(&lds[c * 2048 + roff + 1024]));
        }
        float* row = P1 + ks * 524288 + (hg * 32 + h_loc) * 1024 + b0 * 8;
        *(float4*)(row + f4i * 4)      = m0;
        *(float4*)(row + 32 + f4i * 4) = m1;
    }
}

// ---------------------------------------------------------------------------
// Stage 2. Grid 512 = og4 (32 o, low bits: dw XCD slicing) x bg16 (8 b) x
// ks8 (64 h). Block 256 = 4 waves = 4 h-subchunks of 16.
// Lane = os16 x es4; thread tile 8b x 2o x 2e, o-pair (os, os+16).
// Prologue: H-tile [64 h][8 b][8 e] = product of 4 P1 partials -> LDS.
// Step: 2 coalesced VMEM b64 (dw) + 8 immediate-offset ds_read_b64 (H) +
// 16 pk-VALU. kc-partials combined in reused LDS -> P2.
// ---------------------------------------------------------------------------
__global__ __launch_bounds__(256, 4) void k_stage2(
    const float* __restrict__ dw,   // [512][128][8]
    const float* __restrict__ P1,   // ws: [4][512][128][8]
    float* __restrict__ P2)         // ws: [8][128][128][8]
{
    __shared__ float lds[8192];              // 32 KB: H-tile [0,4096) then combine
    const int t    = threadIdx.x;
    const int lane = t & 63;
    const int kc   = t >> 6;                 // 0..3
    const int es   = lane & 3;
    const int os   = lane >> 2;              // 0..15
    const int og   = blockIdx.x & 3;
    const int bg   = (blockIdx.x >> 2) & 15;
    const int ks   = blockIdx.x >> 6;        // 0..7
    const int b0   = bg * 8;
    const int h0   = ks * 64;

    // H-tile: product of the 4 i-split partials, layout [hl][b][e]
    {
        float4* ht4 = (float4*)lds;
        #pragma unroll
        for (int k = 0; k < 4; ++k) {
            const int f4  = t + k * 256;     // 0..1023
            const int hl  = f4 >> 4;
            const int rem = f4 & 15;
            const float* q = P1 + (h0 + hl) * 1024 + b0 * 8 + rem * 4;
            float4 m = LD4(q);
            m = f4mul(m, LD4(q + 524288));
            m = f4mul(m, LD4(q + 1048576));
            m = f4mul(m, LD4(q + 1572864));
            ht4[f4] = m;
        }
    }
    __syncthreads();

    const float* pd = dw + (h0 + kc * 16) * 1024 + og * 256 + os * 8 + es * 2;
    const float* hbase = lds + kc * 1024 + es * 2;  // + ii*64 + b*8 (immediates)

    float2 acc[8][2];                        // [b][oo], 32 VGPR
    #pragma unroll
    for (int b = 0; b < 8; ++b) {
        acc[b][0] = make_float2(1.f, 1.f);
        acc[b][1] = make_float2(1.f, 1.f);
    }

    #pragma unroll
    for (int ii = 0; ii < 16; ++ii) {
        const float2 d0 = LD2(pd);           // o = og*32 + os
        const float2 d1 = LD2(pd + 128);     // o = og*32 + os + 16
        pd += 1024;
        #pragma unroll
        for (int b = 0; b < 8; ++b) {
            const float2 hv = LD2(hbase + ii * 64 + b * 8);    // ds_read_b64
            acc[b][0] = f2mul(acc[b][0], f2nfma1(d0, hv));
            acc[b][1] = f2mul(acc[b][1], f2nfma1(d1, hv));
        }
    }

    __syncthreads();                         // H-tile dead; reuse lds
    // part[kc][b][o_loc][e], o_loc = os + oo*16
    #pragma unroll
    for (int b = 0; b < 8; ++b) {
        #pragma unroll
        for (int oo = 0; oo < 2; ++oo)
            *(float2*)&lds[kc * 2048 + b * 256 + (os + oo * 16) * 8 + es * 2]
                = acc[b][oo];
    }
    __syncthreads();

    {   // combine 4 kc; thread -> (b_loc = t>>5, f4i = t&31); segment stores
        const int b_loc = t >> 5;
        const int f4i   = t & 31;            // o_lo*2 + eh
        const int roff  = b_loc * 256 + (f4i >> 1) * 8 + (f4i & 1) * 4;
        float4 m0 = LD4(&lds[roff]);         // o_loc = f4i>>1 (0..15)
        float4 m1 = LD4(&lds[roff + 128]);   // o_loc + 16
        #pragma unroll
        for (int c = 1; c < 4; ++c) {
            m0 = f4mul(m0, LD4(&lds[c * 2048 + roff]));
            m1 = f4mul(m1, LD4(&lds[c * 2048 + roff + 128]));
        }
        float* row = P2 + ks * 131072 + (b0 + b_loc) * 1024 + og * 256;
        *(float4*)(row + f4i * 4)       = m0;
        *(float4*)(row + 128 + f4i * 4) = m1;
    }
}

// ---------------------------------------------------------------------------
// Final: out = 1 - prod over the 8 h-split partials. 4 MB read, 0.5 MB write.
// ---------------------------------------------------------------------------
__global__ __launch_bounds__(256, 4) void k_comb2(
    const float* __restrict__ P2,   // ws: [8][128][128][8]
    float* __restrict__ out)        // [128][128][8]
{
    const int idx4 = blockIdx.x * 256 + threadIdx.x;   // 0..32767
    float4 m = LD4(P2 + idx4 * 4);
    #pragma unroll
    for (int c = 1; c < 8; ++c)
        m = f4mul(m, LD4(P2 + c * 131072 + idx4 * 4));
    const float4 r = make_float4(1.f - m.x, 1.f - m.y, 1.f - m.z, 1.f - m.w);
    *(float4*)(out + idx4 * 4) = r;
}

extern "C" void kernel_launch(void* const* d_in, const int* in_sizes, int n_in,
                              void* d_out, int out_size, void* d_ws, size_t ws_size,
                              hipStream_t stream)
{
    const float* in = (const float*)d_in[0];   // [128][256][8]
    const float* cw = (const float*)d_in[1];   // [256][512][8]
    const float* cs = (const float*)d_in[2];   // [256][512][8]
    const float* dw = (const float*)d_in[3];   // [512][128][8]
    float* outp = (float*)d_out;               // [128][128][8]
    float* P1   = (float*)d_ws;                // 8 MB
    float* P2   = (float*)d_ws + 2097152;      // 4 MB

    k_stage1<<<1024, 256, 0, stream>>>(in, cw, cs, P1);
    k_stage2<<<512, 256, 0, stream>>>(dw, P1, P2);
    k_comb2<<<128, 256, 0, stream>>>(P2, outp);
}

// Round 11
// 138.180 us; speedup vs baseline: 1.1584x; 1.0473x over previous
//
#include <hip/hip_runtime.h>

// EmbedDNF: B=128, IN_F=256, HID=512, OUT=128, E=8 (fp32, e innermost)
//
// impl = 1 - w*(1-xnor) = A + x*Bv ; A = 1 - w*s ; Bv = 2*w*s - w
// H[b,h,e]   = prod_i (A[i,h,e] + x[b,i,e]*Bv[i,h,e])
// out[b,o,e] = 1 - prod_h (1 - dw[h,o,e]*H[b,h,e])
//
// Laws (R4-R10): (1) acc <= 32 VGPR and NO inner-loop restructuring — the
// R7 stage1 loop (2 LD4 VMEM streams + 8 immediate-offset ds_read_b128) is
// the only spill-free config; 4 attempts to "improve" it all spilled.
// (2) broadcast operands live in LDS; (3) no device-scope fences (R9);
// (4) per-graph-node fixed cost ~7-10 us (R1->R2) => fewer kernels wins.
// This round: stage1 = R7 VERBATIM; stage2 fused over full h (8 phases of
// 64 h in-block, kc-combine in LDS) -> no P2, no comb2. 2 kernels total.
//
// ws: P1 [4][512][128][8] fp32 @ 0 (8 MB)  stage1 i-split partials

#define LD4(p) (*(const float4*)(p))

static __device__ __forceinline__ float4 f4mul(float4 a, float4 b) {
    return make_float4(a.x*b.x, a.y*b.y, a.z*b.z, a.w*b.w);
}
static __device__ __forceinline__ float2 f2mul(float2 a, float2 b) {
    return make_float2(a.x*b.x, a.y*b.y);
}
static __device__ __forceinline__ float4 f4fma(float4 a, float4 b, float4 c) {
    return make_float4(fmaf(a.x,b.x,c.x), fmaf(a.y,b.y,c.y),
                       fmaf(a.z,b.z,c.z), fmaf(a.w,b.w,c.w));
}
static __device__ __forceinline__ float4 f4nfma1(float4 d, float4 h) {  // 1-d*h
    return make_float4(fmaf(-d.x,h.x,1.0f), fmaf(-d.y,h.y,1.0f),
                       fmaf(-d.z,h.z,1.0f), fmaf(-d.w,h.w,1.0f));
}

// ---------------------------------------------------------------------------
// Stage 1 — R7 VERBATIM (proven: part of the 97.3 us run; spill-free).
// Grid 1024 = hg16 (32 h, low bits: XCD L2 slicing) x bg16 (8 b) x ks4 (64 i).
// Block 256 = 4 waves = 4 i-subchunks of 16. Lane = eh2 x hl32; thread tile
// 8b x 1h x 4e (acc = 32 VGPR). Prologue: x-tile [8 b][64 i][8 e] -> LDS.
// Step: 2 streaming VMEM (w,s contiguous 1 KB wave-loads) + 8 immediate-
// offset ds_read_b128 broadcasts + ~76 VALU. kc-partials combined in LDS.
// ---------------------------------------------------------------------------
__global__ __launch_bounds__(256, 4) void k_stage1(
    const float* __restrict__ in,   // [128][256][8]
    const float* __restrict__ cw,   // [256][512][8]
    const float* __restrict__ cs,   // [256][512][8]
    float* __restrict__ P1)         // ws: [4][512][128][8]
{
    __shared__ float lds[8192];              // 32 KB: x-tile [0,4096) then combine
    const int t    = threadIdx.x;
    const int lane = t & 63;
    const int kc   = t >> 6;                 // 0..3
    const int eh   = lane & 1;
    const int hl   = lane >> 1;              // 0..31
    const int hg   = blockIdx.x & 15;
    const int bg   = (blockIdx.x >> 4) & 15;
    const int ks   = blockIdx.x >> 8;        // 0..3
    const int b0   = bg * 8;
    const int h    = hg * 32 + hl;
    const int e0   = eh * 4;

    // stage x[b0:+8][ks*64:+64][0:8] -> lds (layout [b][il][e]), coalesced
    {
        float4* xs4 = (float4*)lds;
        #pragma unroll
        for (int k = 0; k < 4; ++k) {
            const int f4  = t + k * 256;     // 0..1023
            const int b   = f4 >> 7;
            const int col = f4 & 127;        // float4 within 512 B row
            xs4[b * 128 + col] = LD4(in + (b0 + b) * 2048 + ks * 512 + col * 4);
        }
    }
    __syncthreads();

    const int i0 = (ks * 4 + kc) * 16;
    const float* pw = cw + i0 * 4096 + h * 8 + e0;
    const float* ps = cs + i0 * 4096 + h * 8 + e0;
    const float* xbase = lds + kc * 128 + e0;   // + b*512 + ii*8 (immediates)

    float4 acc[8];
    #pragma unroll
    for (int b = 0; b < 8; ++b) acc[b] = make_float4(1.f, 1.f, 1.f, 1.f);

    #pragma unroll
    for (int ii = 0; ii < 16; ++ii) {
        const float4 wv = LD4(pw);
        const float4 sv = LD4(ps);
        pw += 4096; ps += 4096;
        const float4 p  = f4mul(wv, sv);
        const float4 A  = make_float4(1.f - p.x, 1.f - p.y, 1.f - p.z, 1.f - p.w);
        const float4 Bv = make_float4(fmaf(2.f, p.x, -wv.x), fmaf(2.f, p.y, -wv.y),
                                      fmaf(2.f, p.z, -wv.z), fmaf(2.f, p.w, -wv.w));
        #pragma unroll
        for (int b = 0; b < 8; ++b) {
            const float4 xv = LD4(xbase + b * 512 + ii * 8);
            acc[b] = f4mul(acc[b], f4fma(xv, Bv, A));
        }
    }

    __syncthreads();                         // x-tile dead; reuse lds
    #pragma unroll
    for (int b = 0; b < 8; ++b)
        *(float4*)&lds[kc * 2048 + b * 256 + hl * 8 + e0] = acc[b];
    __syncthreads();

    {   // combine 4 kc; one (b,h) row of 8 e per thread; 32 B global store
        const int bq  = t >> 5;
        const int hl2 = t & 31;
        const int base = bq * 256 + hl2 * 8;
        float4 m0 = LD4(&lds[base]);
        float4 m1 = LD4(&lds[base + 4]);
        #pragma unroll
        for (int c = 1; c < 4; ++c) {
            m0 = f4mul(m0, LD4(&lds[c * 2048 + base]));
            m1 = f4mul(m1, LD4(&lds[c * 2048 + base + 4]));
        }
        float* q = P1 + ks * 524288 + (hg * 32 + hl2) * 1024 + (b0 + bq) * 8;
        *(float4*)q = m0;
        *(float4*)(q + 4) = m1;
    }
}

// ---------------------------------------------------------------------------
// Stage 2 — fused over full h (replaces stage2 + comb2; NO fences, NO P2).
// Grid 256 = og16 (8 o, low bits: dw XCD slicing) x bg16 (8 b).
// Block 256 = 4 waves; wave kc = h-subchunk within each 64-h phase.
// Lane = es2 x oj8 x bs4; thread tile 2b x 1o x 4e (acc = 8 VGPR).
// Per phase: H-tile [64 h][8 b][8 e] = product of 4 P1 copies -> LDS
// (R7's proven prologue), then 16 steps: 1 dw LD4 (256 B/wave, 4x dup) +
// 2 immediate-offset ds_read_b128 (2-way bank alias = free) + 4 f4-VALU.
// After 8 phases: kc-combine in separate LDS buffer -> out = 1 - prod.
// ---------------------------------------------------------------------------
__global__ __launch_bounds__(256, 4) void k_stage2(
    const float* __restrict__ dw,   // [512][128][8]
    const float* __restrict__ P1,   // ws: [4][512][128][8]
    float* __restrict__ out)        // [128][128][8]
{
    __shared__ float lds[4096];              // 16 KB H-tile (per phase)
    __shared__ float cmb[2048];              // 8 KB kc-combine buffer
    const int t    = threadIdx.x;
    const int lane = t & 63;
    const int kc   = t >> 6;                 // 0..3 (h-subchunk in phase)
    const int es   = lane & 1;
    const int oj   = (lane >> 1) & 7;        // o within block
    const int bs   = lane >> 4;              // 0..3 (b-pair)
    const int og   = blockIdx.x & 15;        // low bits: dw XCD slicing
    const int bg   = blockIdx.x >> 4;
    const int b0   = bg * 8;
    const int o0   = og * 8;
    const int e0   = es * 4;

    float4 acc0 = make_float4(1.f, 1.f, 1.f, 1.f);   // b = bs*2
    float4 acc1 = make_float4(1.f, 1.f, 1.f, 1.f);   // b = bs*2 + 1

    for (int ks = 0; ks < 8; ++ks) {
        const int h0 = ks * 64;
        // H-tile: product of the 4 i-split partials, layout [hl][b][e]
        {
            float4* ht4 = (float4*)lds;
            #pragma unroll
            for (int k = 0; k < 4; ++k) {
                const int f4  = t + k * 256;     // 0..1023
                const int hl  = f4 >> 4;
                const int rem = f4 & 15;         // b*2 + eq
                const float* q = P1 + (h0 + hl) * 1024 + b0 * 8 + rem * 4;
                float4 m = LD4(q);
                m = f4mul(m, LD4(q + 524288));
                m = f4mul(m, LD4(q + 1048576));
                m = f4mul(m, LD4(q + 1572864));
                ht4[f4] = m;
            }
        }
        __syncthreads();

        const float* pd = dw + (h0 + kc * 16) * 1024 + (o0 + oj) * 8 + e0;
        const float* hb = lds + kc * 1024 + bs * 16 + e0;   // + ii*64 (+8)

        #pragma unroll
        for (int ii = 0; ii < 16; ++ii) {
            const float4 dv = LD4(pd);
            pd += 1024;
            const float4 hv0 = LD4(hb + ii * 64);        // b = bs*2
            const float4 hv1 = LD4(hb + ii * 64 + 8);    // b = bs*2+1
            acc0 = f4mul(acc0, f4nfma1(dv, hv0));
            acc1 = f4mul(acc1, f4nfma1(dv, hv1));
        }
        __syncthreads();                     // before next phase's tile write
    }

    // kc-combine: cmb[kc][b_loc][oj][e]
    *(float4*)&cmb[kc * 512 + (bs * 2 + 0) * 64 + oj * 8 + e0] = acc0;
    *(float4*)&cmb[kc * 512 + (bs * 2 + 1) * 64 + oj * 8 + e0] = acc1;
    __syncthreads();

    {   // 512 outputs, 256 threads -> one float2 each; contiguous segments
        const int o2 = t * 2;                // index into [b8][o8][e8]
        float2 m = *(const float2*)&cmb[o2];
        #pragma unroll
        for (int c = 1; c < 4; ++c)
            m = f2mul(m, *(const float2*)&cmb[c * 512 + o2]);
        const int bq  = o2 >> 6;
        const int rem = o2 & 63;             // o_loc*8 + e
        *(float2*)(out + (b0 + bq) * 1024 + o0 * 8 + rem)
            = make_float2(1.f - m.x, 1.f - m.y);
    }
}

extern "C" void kernel_launch(void* const* d_in, const int* in_sizes, int n_in,
                              void* d_out, int out_size, void* d_ws, size_t ws_size,
                              hipStream_t stream)
{
    const float* in = (const float*)d_in[0];   // [128][256][8]
    const float* cw = (const float*)d_in[1];   // [256][512][8]
    const float* cs = (const float*)d_in[2];   // [256][512][8]
    const float* dw = (const float*)d_in[3];   // [512][128][8]
    float* outp = (float*)d_out;               // [128][128][8]
    float* P1   = (float*)d_ws;                // 8 MB used

    k_stage1<<<1024, 256, 0, stream>>>(in, cw, cs, P1);
    k_stage2<<<256, 256, 0, stream>>>(dw, P1, outp);
}

// Round 12
// 97.149 us; speedup vs baseline: 1.6476x; 1.4223x over previous
//
#include <hip/hip_runtime.h>

// EmbedDNF: B=128, IN_F=256, HID=512, OUT=128, E=8 (fp32, e innermost)
//
// impl = 1 - w*(1-xnor) = A + x*Bv ; A = 1 - w*s ; Bv = 2*w*s - w
// H[b,h,e]   = prod_i (A[i,h,e] + x[b,i,e]*Bv[i,h,e])
// out[b,o,e] = 1 - prod_h (1 - dw[h,o,e]*H[b,h,e])
//
// Laws (R4-R11): (1) acc <= 32 VGPR, inner loop = 2 VMEM streams +
// immediate-offset LDS broadcasts, NO restructuring (4 spill regressions);
// (2) broadcast operands in LDS; (3) no device-scope fences (R9);
// (4) fewer-but-starved kernels lose: keep >= 4 blocks/CU resident (R11);
// (5) this round: same R7 inner structure, 2x grid via deeper K-split ->
// 32 waves/CU stage1, 16 waves/CU stage2 (latency-bound kernels).
//
// ws: P1 [8][512][128][8] fp32 @ 0        (16 MB)  stage1 i-split partials
//     P2 [16][128][128][8] fp32 @ 4194304 (8 MB)   stage2 h-split partials

#define LD4(p) (*(const float4*)(p))

static __device__ __forceinline__ float4 f4mul(float4 a, float4 b) {
    return make_float4(a.x*b.x, a.y*b.y, a.z*b.z, a.w*b.w);
}
static __device__ __forceinline__ float4 f4fma(float4 a, float4 b, float4 c) {
    return make_float4(fmaf(a.x,b.x,c.x), fmaf(a.y,b.y,c.y),
                       fmaf(a.z,b.z,c.z), fmaf(a.w,b.w,c.w));
}
static __device__ __forceinline__ float4 f4nfma1(float4 d, float4 h) {  // 1-d*h
    return make_float4(fmaf(-d.x,h.x,1.0f), fmaf(-d.y,h.y,1.0f),
                       fmaf(-d.z,h.z,1.0f), fmaf(-d.w,h.w,1.0f));
}

// ---------------------------------------------------------------------------
// Stage 1. Grid 2048 = hg16 (32 h, low bits: XCD L2 slicing) x bg16 (8 b) x
// ks8 (32 i). Block 256 = 4 waves = 4 i-subchunks of 8. Lane = eh2 x hl32;
// thread tile 8b x 1h x 4e (acc = 32 VGPR, R7-proven).
// Prologue: x-tile [8 b][32 i][8 e] (8 KB) -> LDS, coalesced.
// Step: 2 streaming VMEM (w,s contiguous 1 KB wave-loads) + 8 immediate-
// offset ds_read_b128 broadcasts + ~60 VALU.  8 steps.
// kc-partials combined in 2 phases of 4 b (16 KB LDS total, reused buffer).
// 16 KB LDS + ~64 VGPR -> up to 8 blocks/CU resident (32 waves/CU).
// ---------------------------------------------------------------------------
__global__ __launch_bounds__(256, 4) void k_stage1(
    const float* __restrict__ in,   // [128][256][8]
    const float* __restrict__ cw,   // [256][512][8]
    const float* __restrict__ cs,   // [256][512][8]
    float* __restrict__ P1)         // ws: [8][512][128][8]
{
    __shared__ float lds[4096];              // 16 KB: x-tile [0,2048) then combine
    const int t    = threadIdx.x;
    const int lane = t & 63;
    const int kc   = t >> 6;                 // 0..3
    const int eh   = lane & 1;
    const int hl   = lane >> 1;              // 0..31
    const int hg   = blockIdx.x & 15;
    const int bg   = (blockIdx.x >> 4) & 15;
    const int ks   = blockIdx.x >> 8;        // 0..7
    const int b0   = bg * 8;
    const int h    = hg * 32 + hl;
    const int e0   = eh * 4;

    // stage x[b0:+8][ks*32:+32][0:8] -> lds (layout [b][il][e]), coalesced:
    // each wave loads one b-row (1 KB contiguous)
    {
        float4* xs4 = (float4*)lds;
        #pragma unroll
        for (int k = 0; k < 2; ++k) {
            const int f4  = t + k * 256;     // 0..511
            const int b   = f4 >> 6;
            const int col = f4 & 63;         // float4 within 256-float row
            xs4[f4] = LD4(in + (b0 + b) * 2048 + ks * 256 + col * 4);
        }
    }
    __syncthreads();

    const int i0 = ks * 32 + kc * 8;
    const float* pw = cw + i0 * 4096 + h * 8 + e0;
    const float* ps = cs + i0 * 4096 + h * 8 + e0;
    const float* xbase = lds + kc * 64 + e0;    // + b*256 + ii*8 (immediates)

    float4 acc[8];
    #pragma unroll
    for (int b = 0; b < 8; ++b) acc[b] = make_float4(1.f, 1.f, 1.f, 1.f);

    #pragma unroll
    for (int ii = 0; ii < 8; ++ii) {
        const float4 wv = LD4(pw);
        const float4 sv = LD4(ps);
        pw += 4096; ps += 4096;
        const float4 p  = f4mul(wv, sv);
        const float4 A  = make_float4(1.f - p.x, 1.f - p.y, 1.f - p.z, 1.f - p.w);
        const float4 Bv = make_float4(fmaf(2.f, p.x, -wv.x), fmaf(2.f, p.y, -wv.y),
                                      fmaf(2.f, p.z, -wv.z), fmaf(2.f, p.w, -wv.w));
        #pragma unroll
        for (int b = 0; b < 8; ++b) {
            const float4 xv = LD4(xbase + b * 256 + ii * 8);
            acc[b] = f4mul(acc[b], f4fma(xv, Bv, A));
        }
    }

    __syncthreads();                         // x-tile dead; reuse lds
    // 2 phases of 4 b: partial[kc][j4][hl32][e8] = 1024 floats per kc
    #pragma unroll
    for (int phase = 0; phase < 2; ++phase) {
        if (phase) __syncthreads();          // protect phase-0 reads
        #pragma unroll
        for (int j = 0; j < 4; ++j)
            *(float4*)&lds[kc * 1024 + j * 256 + hl * 8 + e0] = acc[phase * 4 + j];
        __syncthreads();
        {   // combine 4 kc; thread t -> one float4 of the 1024-float tile
            const int o4 = t * 4;            // j*256 + hl2*8 + eq*4
            float4 m = LD4(&lds[o4]);
            #pragma unroll
            for (int c = 1; c < 4; ++c) m = f4mul(m, LD4(&lds[c * 1024 + o4]));
            const int j   = o4 >> 8;
            const int hl2 = (o4 >> 3) & 31;
            const int eq  = o4 & 7;          // 0 or 4
            *(float4*)(P1 + ks * 524288 + (hg * 32 + hl2) * 1024
                          + (b0 + phase * 4 + j) * 8 + eq) = m;
        }
    }
}

// ---------------------------------------------------------------------------
// Stage 2. Grid 1024 = og4 (32 o, low bits: dw XCD slicing) x bg16 (8 b) x
// ks16 (32 h). Block 256 = 4 waves = 4 h-subchunks of 8. Lane = eh2 x ol32;
// thread tile 8b x 1o x 4e (acc = 32 VGPR, R7-proven).
// Prologue: H-tile [32 h][8 b][8 e] (8 KB) = product of 8 P1 copies -> LDS.
// Step: 1 streaming VMEM (dw contiguous 1 KB wave-load) + 8 immediate-offset
// ds_read_b128 broadcasts + 64 VALU.  8 steps.
// kc-partials combined in 2 phases of 4 b; ks-partials -> P2.
// ---------------------------------------------------------------------------
__global__ __launch_bounds__(256, 4) void k_stage2(
    const float* __restrict__ dw,   // [512][128][8]
    const float* __restrict__ P1,   // ws: [8][512][128][8]
    float* __restrict__ P2)         // ws: [16][128][128][8]
{
    __shared__ float lds[4096];              // 16 KB: H-tile [0,2048) then combine
    const int t    = threadIdx.x;
    const int lane = t & 63;
    const int kc   = t >> 6;                 // 0..3
    const int eh   = lane & 1;
    const int ol   = lane >> 1;              // 0..31
    const int og   = blockIdx.x & 3;
    const int bg   = (blockIdx.x >> 2) & 15;
    const int ks   = blockIdx.x >> 6;        // 0..15
    const int b0   = bg * 8;
    const int o    = og * 32 + ol;
    const int e0   = eh * 4;
    const int h0   = ks * 32;

    // H-tile: product of the 8 i-split partials, layout [hl][b][e]
    {
        float4* ht4 = (float4*)lds;
        #pragma unroll
        for (int k = 0; k < 2; ++k) {
            const int f4  = t + k * 256;     // 0..511
            const int hl  = f4 >> 4;
            const int rem = f4 & 15;         // b*2 + eq
            const float* q = P1 + (h0 + hl) * 1024 + b0 * 8 + rem * 4;
            float4 m = LD4(q);
            #pragma unroll
            for (int c = 1; c < 8; ++c) m = f4mul(m, LD4(q + c * 524288));
            ht4[f4] = m;
        }
    }
    __syncthreads();

    const float* pd = dw + (h0 + kc * 8) * 1024 + o * 8 + e0;
    const float* hbase = lds + kc * 512 + e0;   // + ii*64 + b*8 (immediates)

    float4 acc[8];
    #pragma unroll
    for (int b = 0; b < 8; ++b) acc[b] = make_float4(1.f, 1.f, 1.f, 1.f);

    #pragma unroll
    for (int ii = 0; ii < 8; ++ii) {
        const float4 dv = LD4(pd);
        pd += 1024;
        #pragma unroll
        for (int b = 0; b < 8; ++b) {
            const float4 hv = LD4(hbase + ii * 64 + b * 8);
            acc[b] = f4mul(acc[b], f4nfma1(dv, hv));
        }
    }

    __syncthreads();                         // H-tile dead; reuse lds
    // 2 phases of 4 b: partial[kc][j4][ol32][e8] = 1024 floats per kc
    #pragma unroll
    for (int phase = 0; phase < 2; ++phase) {
        if (phase) __syncthreads();
        #pragma unroll
        for (int j = 0; j < 4; ++j)
            *(float4*)&lds[kc * 1024 + j * 256 + ol * 8 + e0] = acc[phase * 4 + j];
        __syncthreads();
        {
            const int o4 = t * 4;            // j*256 + ol2*8 + eq*4
            float4 m = LD4(&lds[o4]);
            #pragma unroll
            for (int c = 1; c < 4; ++c) m = f4mul(m, LD4(&lds[c * 1024 + o4]));
            const int j   = o4 >> 8;
            const int ol2 = (o4 >> 3) & 31;
            const int eq  = o4 & 7;
            *(float4*)(P2 + ks * 131072 + (b0 + phase * 4 + j) * 1024
                          + (og * 32 + ol2) * 8 + eq) = m;
        }
    }
}

// ---------------------------------------------------------------------------
// Final: out = 1 - prod over the 16 h-split partials. 8 MB read, 0.5 MB write.
// 16 independent loads per thread -> deep MLP.
// ---------------------------------------------------------------------------
__global__ __launch_bounds__(256, 4) void k_comb2(
    const float* __restrict__ P2,   // ws: [16][128][128][8]
    float* __restrict__ out)        // [128][128][8]
{
    const int idx4 = blockIdx.x * 256 + threadIdx.x;   // 0..32767
    float4 m = LD4(P2 + idx4 * 4);
    #pragma unroll
    for (int c = 1; c < 16; ++c)
        m = f4mul(m, LD4(P2 + c * 131072 + idx4 * 4));
    const float4 r = make_float4(1.f - m.x, 1.f - m.y, 1.f - m.z, 1.f - m.w);
    *(float4*)(out + idx4 * 4) = r;
}

extern "C" void kernel_launch(void* const* d_in, const int* in_sizes, int n_in,
                              void* d_out, int out_size, void* d_ws, size_t ws_size,
                              hipStream_t stream)
{
    const float* in = (const float*)d_in[0];   // [128][256][8]
    const float* cw = (const float*)d_in[1];   // [256][512][8]
    const float* cs = (const float*)d_in[2];   // [256][512][8]
    const float* dw = (const float*)d_in[3];   // [512][128][8]
    float* outp = (float*)d_out;               // [128][128][8]
    float* P1   = (float*)d_ws;                // 16 MB
    float* P2   = (float*)d_ws + 4194304;      // 8 MB

    k_stage1<<<2048, 256, 0, stream>>>(in, cw, cs, P1);
    k_stage2<<<1024, 256, 0, stream>>>(dw, P1, P2);
    k_comb2<<<128, 256, 0, stream>>>(P2, outp);
}